// Round 7
// baseline (229.600 us; speedup 1.0000x reference)
//
#include <hip/hip_runtime.h>
#include <math.h>

// out = gamma * (S * x) + x  ==  (1 + gamma*S) * x
// S = (p+1)/(pi*(N-1)^2) * sum_{i,j in [0,N)} cos(q * atan2(j, i)),  p=2, q=1, N=256
// S is data-independent -> computed on host once; gamma read on device (restored each call).
//
// v7 == v6 with UNROLL 4 -> 8 (single-variable change). 32KB contiguous tile
// per block, 4096 blocks; 8 independent global_load_dwordx4 in flight per
// thread before any dependent store. Block-uniform bounds branch keeps VGPR
// low (v4's 104-VGPR blowup was per-access exec-mask guards, not ILP depth).

typedef float v4f __attribute__((ext_vector_type(4)));

#define UNROLL 8
#define BLOCK  256

__global__ __launch_bounds__(BLOCK) void zam_scale_v7(
    const v4f* __restrict__ x,
    const float* __restrict__ gamma,
    v4f* __restrict__ out,
    float S, int n4, int nfloat)
{
    int base = (int)blockIdx.x * (BLOCK * UNROLL);
    int t = (int)threadIdx.x;
    float scale = fmaf(gamma[0], S, 1.0f);

    if (base + BLOCK * UNROLL <= n4) {
        // fast path: whole 2048-float4 tile in bounds (block-uniform branch)
        v4f v[UNROLL];
#pragma unroll
        for (int u = 0; u < UNROLL; ++u)
            v[u] = x[base + t + u * BLOCK];      // 8 independent 16B loads
#pragma unroll
        for (int u = 0; u < UNROLL; ++u)
            out[base + t + u * BLOCK] = v[u] * scale;
    } else {
        // tail block: guarded scalar-float loop over this block's span
        const float* xf = (const float*)x;
        float* of = (float*)out;
        int fbase = base * 4;                    // first float of this tile
#pragma unroll
        for (int u = 0; u < UNROLL * 4; ++u) {
            int idx = fbase + t + u * BLOCK;
            if (idx < nfloat) of[idx] = xf[idx] * scale;
        }
    }
}

static float compute_S() {
    const int N = 256;
    const double p = 2.0, q = 1.0;
    double s = 0.0;
    for (int i = 0; i < N; ++i) {
        for (int j = 0; j < N; ++j) {
            // atan2(0,0) == 0 in C, matching jnp.arctan2(0,0) == 0
            s += cos(q * atan2((double)j, (double)i));
        }
    }
    return (float)(s * (p + 1.0) / (M_PI * (double)(N - 1) * (double)(N - 1)));
}

extern "C" void kernel_launch(void* const* d_in, const int* in_sizes, int n_in,
                              void* d_out, int out_size, void* d_ws, size_t ws_size,
                              hipStream_t stream) {
    const float* x     = (const float*)d_in[0];
    const float* gamma = (const float*)d_in[1];
    float* out         = (float*)d_out;

    static const float S = compute_S();  // deterministic host constant

    int nfloat = out_size;               // floats (8*64*256*256 = 33554432)
    int n4 = nfloat / 4;                 // float4 count (8388608, divisible)
    int tile_floats = BLOCK * UNROLL * 4;           // 8192 floats per block
    int grid = (nfloat + tile_floats - 1) / tile_floats;  // 4096 for bench size
    if (grid < 1) grid = 1;              // tiny-dispatch safety

    zam_scale_v7<<<grid, BLOCK, 0, stream>>>(
        (const v4f*)x, gamma, (v4f*)out, S, n4, nfloat);
}